// Round 1
// baseline (118.911 us; speedup 1.0000x reference)
//
#include <hip/hip_runtime.h>
#include <math.h>

#define ROW 345            // 115 joints * 3
#define NFRAMES 100000
#define OUTROWS 200
#define FEAT 1198

__global__ void zero_ws_kernel(int* ws) {
    if (threadIdx.x == 0) ws[0] = 0;
}

// diff += (#nonzero lefth) - (#nonzero righth), over all frames.
// lefth: floats [120,183) of each row; righth: [282,345).
__global__ void count_kernel(const float* __restrict__ x, int* __restrict__ diff) {
    const long long total = (long long)NFRAMES * 126;
    int local = 0;
    for (long long idx = (long long)blockIdx.x * blockDim.x + threadIdx.x;
         idx < total;
         idx += (long long)gridDim.x * blockDim.x) {
        int frame = (int)(idx / 126);
        int r = (int)(idx - (long long)frame * 126);
        int off = frame * ROW + (r < 63 ? 120 + r : 219 + r);
        float v = x[off];
        if (v != v) v = 0.0f;            // NaN -> 0
        int nz = (v != 0.0f) ? 1 : 0;
        local += (r < 63) ? nz : -nz;
    }
    // wave-64 reduction
    #pragma unroll
    for (int s = 32; s > 0; s >>= 1) local += __shfl_down(local, s, 64);
    if ((threadIdx.x & 63) == 0 && local != 0) atomicAdd(diff, local);
}

__global__ void feat_kernel(const float* __restrict__ x,
                            const int* __restrict__ diffp,
                            float* __restrict__ out) {
    __shared__ float xf0[86][3];
    __shared__ float xf1[86][3];
    __shared__ float s_handsum;

    const int t = blockIdx.x;
    const bool cond = (*diffp) > 0;
    const int handbase = cond ? 120 : 282;

    // Build xfeat rows t and t+1 (86 joints x 3), NaN-cleaned, x-coord mirrored if cond
    for (int q = threadIdx.x; q < 2 * 258; q += blockDim.x) {
        int which = q / 258;
        int e = q - which * 258;
        int k = e / 3, c = e - k * 3;
        int src;
        if (k < 21)      src = handbase + k * 3 + c;          // hand
        else if (k < 46) src = 183 + (k - 21) * 3 + c;        // pose (joints 61:86)
        else             src = (k - 46) * 3 + c;              // lip (joints 0:40)
        int row = t + which;
        float v = x[(long long)row * ROW + src];
        if (v != v) v = 0.0f;
        if (c == 0 && cond) v = -v;
        if (which == 0) xf0[k][c] = v; else xf1[k][c] = v;
    }
    __syncthreads();

    if (threadIdx.x == 0) {
        // hand_mask uses raw (un-mirrored) selected-hand values
        float s = 0.0f;
        for (int k = 0; k < 21; ++k)
            for (int c = 0; c < 3; ++c) {
                float v = xf0[k][c];
                if (c == 0 && cond) v = -v;   // undo mirror
                s += v;
            }
        s_handsum = s;
    }
    __syncthreads();

    const float hand_mask = (s_handsum != 0.0f) ? 1.0f : 0.0f;
    float* o = out + (long long)t * FEAT;

    for (int q = threadIdx.x; q < FEAT; q += blockDim.x) {
        float v;
        if (q < 63) {                      // xfeat[:21,:3]
            int k = q / 3, c = q % 3; v = xf0[k][c];
        } else if (q < 113) {              // xfeat[21:46,:2]
            int p = q - 63; int k = 21 + p / 2, c = p & 1; v = xf0[k][c];
        } else if (q < 153) {              // xfeat[46:66,:2]
            int p = q - 113; int k = 46 + p / 2, c = p & 1; v = xf0[k][c];
        } else if (q < 216) {              // dxyz[:21,:3]
            int p = q - 153; int k = p / 3, c = p % 3; v = xf0[k][c] - xf1[k][c];
        } else if (q < 266) {              // dxyz[21:46,:2]
            int p = q - 216; int k = 21 + p / 2, c = p & 1; v = xf0[k][c] - xf1[k][c];
        } else if (q < 306) {              // dxyz[46:66,:2]
            int p = q - 266; int k = 46 + p / 2, c = p & 1; v = xf0[k][c] - xf1[k][c];
        } else if (q < 516) {              // hdist: 21 joints, 3D, 210 pairs
            int p = q - 306, n = 21, i = 0, rem = p;
            while (rem >= n - 1 - i) { rem -= n - 1 - i; ++i; }
            int j = i + 1 + rem;
            float dx = xf0[i][0] - xf0[j][0];
            float dy = xf0[i][1] - xf0[j][1];
            float dz = xf0[i][2] - xf0[j][2];
            v = sqrtf(dx * dx + dy * dy + dz * dz);
        } else if (q < 816) {              // pdist: joints 21:46, 2D, 300 pairs
            int p = q - 516, n = 25, i = 0, rem = p;
            while (rem >= n - 1 - i) { rem -= n - 1 - i; ++i; }
            int j = i + 1 + rem; int a = 21 + i, b = 21 + j;
            float dx = xf0[a][0] - xf0[b][0];
            float dy = xf0[a][1] - xf0[b][1];
            v = sqrtf(dx * dx + dy * dy);
        } else if (q < 1006) {             // oldist: joints 46:66, 2D, 190 pairs
            int p = q - 816, n = 20, i = 0, rem = p;
            while (rem >= n - 1 - i) { rem -= n - 1 - i; ++i; }
            int j = i + 1 + rem; int a = 46 + i, b = 46 + j;
            float dx = xf0[a][0] - xf0[b][0];
            float dy = xf0[a][1] - xf0[b][1];
            v = sqrtf(dx * dx + dy * dy);
        } else if (q < 1196) {             // ildist: joints 66:86, 2D, 190 pairs
            int p = q - 1006, n = 20, i = 0, rem = p;
            while (rem >= n - 1 - i) { rem -= n - 1 - i; ++i; }
            int j = i + 1 + rem; int a = 66 + i, b = 66 + j;
            float dx = xf0[a][0] - xf0[b][0];
            float dy = xf0[a][1] - xf0[b][1];
            v = sqrtf(dx * dx + dy * dy);
        } else if (q == 1196) {
            v = hand_mask;
        } else {
            v = hand_mask + 1.0f;
        }
        o[q] = v;
    }
}

extern "C" void kernel_launch(void* const* d_in, const int* in_sizes, int n_in,
                              void* d_out, int out_size, void* d_ws, size_t ws_size,
                              hipStream_t stream) {
    const float* x = (const float*)d_in[0];
    float* out = (float*)d_out;
    int* diff = (int*)d_ws;

    zero_ws_kernel<<<1, 64, 0, stream>>>(diff);
    count_kernel<<<2048, 256, 0, stream>>>(x, diff);
    feat_kernel<<<OUTROWS, 256, 0, stream>>>(x, diff, out);
}

// Round 2
// 72.947 us; speedup vs baseline: 1.6301x; 1.6301x over previous
//
#include <hip/hip_runtime.h>
#include <math.h>

#define ROW 345            // 115 joints * 3
#define NFRAMES 100000
#define OUTROWS 200
#define FEAT 1198
#define UNROLL 8

__global__ void zero_ws_kernel(int* ws) {
    if (threadIdx.x == 0) ws[0] = 0;
}

// diff += (#nonzero lefth) - (#nonzero righth), over all frames.
// lefth: floats [120,183) of each row; righth: [282,345).
// 8-way ILP: 8 independent loads in flight per lane (latency-bound fix).
__global__ void count_kernel(const float* __restrict__ x, int* __restrict__ diff) {
    const unsigned total = NFRAMES * 126u;
    const unsigned nth = gridDim.x * blockDim.x;
    const unsigned tid = blockIdx.x * blockDim.x + threadIdx.x;
    int local = 0;
    for (unsigned base = tid; base < total; base += nth * UNROLL) {
        float v[UNROLL];
        #pragma unroll
        for (int u = 0; u < UNROLL; ++u) {
            unsigned idx = base + (unsigned)u * nth;
            unsigned id = (idx < total) ? idx : 0u;       // clamp; masked below
            unsigned f = id / 126u;                        // magic-mul, 32-bit
            unsigned r = id - f * 126u;
            unsigned off = f * 345u + 120u + r + (r >= 63u ? 99u : 0u);
            v[u] = x[off];
        }
        #pragma unroll
        for (int u = 0; u < UNROLL; ++u) {
            unsigned idx = base + (unsigned)u * nth;
            if (idx < total) {
                float w = v[u];
                if (w != w) w = 0.0f;                      // NaN -> 0
                unsigned f = idx / 126u;
                unsigned r = idx - f * 126u;
                int nz = (w != 0.0f) ? 1 : 0;
                local += (r < 63u) ? nz : -nz;
            }
        }
    }
    #pragma unroll
    for (int s = 32; s > 0; s >>= 1) local += __shfl_down(local, s, 64);
    if ((threadIdx.x & 63) == 0 && local != 0) atomicAdd(diff, local);
}

__global__ void feat_kernel(const float* __restrict__ x,
                            const int* __restrict__ diffp,
                            float* __restrict__ out) {
    __shared__ float xf0[86][3];
    __shared__ float xf1[86][3];
    __shared__ float s_handsum;

    const int t = blockIdx.x;
    const bool cond = (*diffp) > 0;
    const int handbase = cond ? 120 : 282;

    // Build xfeat rows t and t+1 (86 joints x 3), NaN-cleaned, x-coord mirrored if cond
    for (int q = threadIdx.x; q < 2 * 258; q += blockDim.x) {
        int which = q / 258;
        int e = q - which * 258;
        int k = e / 3, c = e - k * 3;
        int src;
        if (k < 21)      src = handbase + k * 3 + c;          // hand
        else if (k < 46) src = 183 + (k - 21) * 3 + c;        // pose (joints 61:86)
        else             src = (k - 46) * 3 + c;              // lip (joints 0:40)
        int row = t + which;
        float v = x[(long long)row * ROW + src];
        if (v != v) v = 0.0f;
        if (c == 0 && cond) v = -v;
        if (which == 0) xf0[k][c] = v; else xf1[k][c] = v;
    }
    __syncthreads();

    if (threadIdx.x == 0) {
        // hand_mask uses raw (un-mirrored) selected-hand values
        float s = 0.0f;
        for (int k = 0; k < 21; ++k)
            for (int c = 0; c < 3; ++c) {
                float v = xf0[k][c];
                if (c == 0 && cond) v = -v;   // undo mirror
                s += v;
            }
        s_handsum = s;
    }
    __syncthreads();

    const float hand_mask = (s_handsum != 0.0f) ? 1.0f : 0.0f;
    float* o = out + (long long)t * FEAT;

    for (int q = threadIdx.x; q < FEAT; q += blockDim.x) {
        float v;
        if (q < 63) {                      // xfeat[:21,:3]
            int k = q / 3, c = q % 3; v = xf0[k][c];
        } else if (q < 113) {              // xfeat[21:46,:2]
            int p = q - 63; int k = 21 + p / 2, c = p & 1; v = xf0[k][c];
        } else if (q < 153) {              // xfeat[46:66,:2]
            int p = q - 113; int k = 46 + p / 2, c = p & 1; v = xf0[k][c];
        } else if (q < 216) {              // dxyz[:21,:3]
            int p = q - 153; int k = p / 3, c = p % 3; v = xf0[k][c] - xf1[k][c];
        } else if (q < 266) {              // dxyz[21:46,:2]
            int p = q - 216; int k = 21 + p / 2, c = p & 1; v = xf0[k][c] - xf1[k][c];
        } else if (q < 306) {              // dxyz[46:66,:2]
            int p = q - 266; int k = 46 + p / 2, c = p & 1; v = xf0[k][c] - xf1[k][c];
        } else if (q < 516) {              // hdist: 21 joints, 3D, 210 pairs
            int p = q - 306, n = 21, i = 0, rem = p;
            while (rem >= n - 1 - i) { rem -= n - 1 - i; ++i; }
            int j = i + 1 + rem;
            float dx = xf0[i][0] - xf0[j][0];
            float dy = xf0[i][1] - xf0[j][1];
            float dz = xf0[i][2] - xf0[j][2];
            v = sqrtf(dx * dx + dy * dy + dz * dz);
        } else if (q < 816) {              // pdist: joints 21:46, 2D, 300 pairs
            int p = q - 516, n = 25, i = 0, rem = p;
            while (rem >= n - 1 - i) { rem -= n - 1 - i; ++i; }
            int j = i + 1 + rem; int a = 21 + i, b = 21 + j;
            float dx = xf0[a][0] - xf0[b][0];
            float dy = xf0[a][1] - xf0[b][1];
            v = sqrtf(dx * dx + dy * dy);
        } else if (q < 1006) {             // oldist: joints 46:66, 2D, 190 pairs
            int p = q - 816, n = 20, i = 0, rem = p;
            while (rem >= n - 1 - i) { rem -= n - 1 - i; ++i; }
            int j = i + 1 + rem; int a = 46 + i, b = 46 + j;
            float dx = xf0[a][0] - xf0[b][0];
            float dy = xf0[a][1] - xf0[b][1];
            v = sqrtf(dx * dx + dy * dy);
        } else if (q < 1196) {             // ildist: joints 66:86, 2D, 190 pairs
            int p = q - 1006, n = 20, i = 0, rem = p;
            while (rem >= n - 1 - i) { rem -= n - 1 - i; ++i; }
            int j = i + 1 + rem; int a = 66 + i, b = 66 + j;
            float dx = xf0[a][0] - xf0[b][0];
            float dy = xf0[a][1] - xf0[b][1];
            v = sqrtf(dx * dx + dy * dy);
        } else if (q == 1196) {
            v = hand_mask;
        } else {
            v = hand_mask + 1.0f;
        }
        o[q] = v;
    }
}

extern "C" void kernel_launch(void* const* d_in, const int* in_sizes, int n_in,
                              void* d_out, int out_size, void* d_ws, size_t ws_size,
                              hipStream_t stream) {
    const float* x = (const float*)d_in[0];
    float* out = (float*)d_out;
    int* diff = (int*)d_ws;

    zero_ws_kernel<<<1, 64, 0, stream>>>(diff);
    count_kernel<<<1024, 256, 0, stream>>>(x, diff);
    feat_kernel<<<OUTROWS, 256, 0, stream>>>(x, diff, out);
}

// Round 3
// 27.872 us; speedup vs baseline: 4.2663x; 2.6172x over previous
//
#include <hip/hip_runtime.h>
#include <math.h>

#define ROW 345            // 115 joints * 3
#define NFRAMES 100000
#define OUTROWS 200
#define FEAT 1198
#define FR_PER_BLOCK 32    // frames per block (exact: 3125 * 32 = 100000)
#define DEPTH 16           // independent loads in flight per thread

__global__ void zero_ws_kernel(int* ws) {
    if (threadIdx.x == 0) ws[0] = 0;
}

// diff += (#nonzero lefth) - (#nonzero righth) over all frames.
// lefth: floats [120,183) of each row; righth: [282,345) (63 floats each).
// Pure affine addressing: no div, no clamp, no bounds check. 16 loads in
// flight per lane, one atomic per block.
__global__ void count_kernel(const float* __restrict__ x, int* __restrict__ diff) {
    const int tid  = threadIdx.x;
    const int half = tid >> 7;           // 0: even frame of pair, 1: odd
    const int elem = tid & 127;          // 0..127; valid work for elem < 126
    // col: elem 0..62 -> left 120+elem (120..182); 63..125 -> right 219+elem (282..344)
    const int col  = (elem < 63) ? (120 + elem) : (219 + elem);
    const int f0   = blockIdx.x * FR_PER_BLOCK + half;
    const float* p = x + (size_t)f0 * ROW + col;

    float v[DEPTH];
    #pragma unroll
    for (int u = 0; u < DEPTH; ++u)
        v[u] = p[(size_t)u * 2 * ROW];   // frames f0, f0+2, ..., f0+30

    int local = 0;
    #pragma unroll
    for (int u = 0; u < DEPTH; ++u) {
        float w = v[u];
        local += (w == w && w != 0.0f) ? 1 : 0;   // NaN -> 0, count nonzero
    }
    // sign: left +, right -, idle lanes (elem 126/127) contribute 0
    int sl = (elem < 63) ? local : ((elem < 126) ? -local : 0);

    #pragma unroll
    for (int s = 32; s > 0; s >>= 1) sl += __shfl_down(sl, s, 64);
    __shared__ int red[4];
    if ((tid & 63) == 0) red[tid >> 6] = sl;
    __syncthreads();
    if (tid == 0) {
        int t = red[0] + red[1] + red[2] + red[3];
        if (t != 0) atomicAdd(diff, t);
    }
}

__global__ void feat_kernel(const float* __restrict__ x,
                            const int* __restrict__ diffp,
                            float* __restrict__ out) {
    __shared__ float xf0[86][3];
    __shared__ float xf1[86][3];
    __shared__ float s_handsum;

    const int t = blockIdx.x;
    const bool cond = (*diffp) > 0;
    const int handbase = cond ? 120 : 282;

    // Build xfeat rows t and t+1 (86 joints x 3), NaN-cleaned, x-coord mirrored if cond
    for (int q = threadIdx.x; q < 2 * 258; q += blockDim.x) {
        int which = q / 258;
        int e = q - which * 258;
        int k = e / 3, c = e - k * 3;
        int src;
        if (k < 21)      src = handbase + k * 3 + c;          // hand
        else if (k < 46) src = 183 + (k - 21) * 3 + c;        // pose (joints 61:86)
        else             src = (k - 46) * 3 + c;              // lip (joints 0:40)
        int row = t + which;
        float v = x[(long long)row * ROW + src];
        if (v != v) v = 0.0f;
        if (c == 0 && cond) v = -v;
        if (which == 0) xf0[k][c] = v; else xf1[k][c] = v;
    }
    __syncthreads();

    if (threadIdx.x == 0) {
        // hand_mask uses raw (un-mirrored) selected-hand values
        float s = 0.0f;
        for (int k = 0; k < 21; ++k)
            for (int c = 0; c < 3; ++c) {
                float v = xf0[k][c];
                if (c == 0 && cond) v = -v;   // undo mirror
                s += v;
            }
        s_handsum = s;
    }
    __syncthreads();

    const float hand_mask = (s_handsum != 0.0f) ? 1.0f : 0.0f;
    float* o = out + (long long)t * FEAT;

    for (int q = threadIdx.x; q < FEAT; q += blockDim.x) {
        float v;
        if (q < 63) {                      // xfeat[:21,:3]
            int k = q / 3, c = q % 3; v = xf0[k][c];
        } else if (q < 113) {              // xfeat[21:46,:2]
            int p = q - 63; int k = 21 + p / 2, c = p & 1; v = xf0[k][c];
        } else if (q < 153) {              // xfeat[46:66,:2]
            int p = q - 113; int k = 46 + p / 2, c = p & 1; v = xf0[k][c];
        } else if (q < 216) {              // dxyz[:21,:3]
            int p = q - 153; int k = p / 3, c = p % 3; v = xf0[k][c] - xf1[k][c];
        } else if (q < 266) {              // dxyz[21:46,:2]
            int p = q - 216; int k = 21 + p / 2, c = p & 1; v = xf0[k][c] - xf1[k][c];
        } else if (q < 306) {              // dxyz[46:66,:2]
            int p = q - 266; int k = 46 + p / 2, c = p & 1; v = xf0[k][c] - xf1[k][c];
        } else if (q < 516) {              // hdist: 21 joints, 3D, 210 pairs
            int p = q - 306, n = 21, i = 0, rem = p;
            while (rem >= n - 1 - i) { rem -= n - 1 - i; ++i; }
            int j = i + 1 + rem;
            float dx = xf0[i][0] - xf0[j][0];
            float dy = xf0[i][1] - xf0[j][1];
            float dz = xf0[i][2] - xf0[j][2];
            v = sqrtf(dx * dx + dy * dy + dz * dz);
        } else if (q < 816) {              // pdist: joints 21:46, 2D, 300 pairs
            int p = q - 516, n = 25, i = 0, rem = p;
            while (rem >= n - 1 - i) { rem -= n - 1 - i; ++i; }
            int j = i + 1 + rem; int a = 21 + i, b = 21 + j;
            float dx = xf0[a][0] - xf0[b][0];
            float dy = xf0[a][1] - xf0[b][1];
            v = sqrtf(dx * dx + dy * dy);
        } else if (q < 1006) {             // oldist: joints 46:66, 2D, 190 pairs
            int p = q - 816, n = 20, i = 0, rem = p;
            while (rem >= n - 1 - i) { rem -= n - 1 - i; ++i; }
            int j = i + 1 + rem; int a = 46 + i, b = 46 + j;
            float dx = xf0[a][0] - xf0[b][0];
            float dy = xf0[a][1] - xf0[b][1];
            v = sqrtf(dx * dx + dy * dy);
        } else if (q < 1196) {             // ildist: joints 66:86, 2D, 190 pairs
            int p = q - 1006, n = 20, i = 0, rem = p;
            while (rem >= n - 1 - i) { rem -= n - 1 - i; ++i; }
            int j = i + 1 + rem; int a = 66 + i, b = 66 + j;
            float dx = xf0[a][0] - xf0[b][0];
            float dy = xf0[a][1] - xf0[b][1];
            v = sqrtf(dx * dx + dy * dy);
        } else if (q == 1196) {
            v = hand_mask;
        } else {
            v = hand_mask + 1.0f;
        }
        o[q] = v;
    }
}

extern "C" void kernel_launch(void* const* d_in, const int* in_sizes, int n_in,
                              void* d_out, int out_size, void* d_ws, size_t ws_size,
                              hipStream_t stream) {
    const float* x = (const float*)d_in[0];
    float* out = (float*)d_out;
    int* diff = (int*)d_ws;

    zero_ws_kernel<<<1, 64, 0, stream>>>(diff);
    count_kernel<<<NFRAMES / FR_PER_BLOCK, 256, 0, stream>>>(x, diff);
    feat_kernel<<<OUTROWS, 256, 0, stream>>>(x, diff, out);
}